// Round 2
// baseline (240.663 us; speedup 1.0000x reference)
//
#include <hip/hip_runtime.h>

// Spherical: out = x * |s|  (x: 8192x4096 fp32, s: scalar fp32)
// Pure streaming scale — memory-bound, zero reuse.
//
// R2 changes vs R1 (83.8 us kernel, regression) and R0 (~63 us kernel):
//  - Back to FLAT exact-cover grid (no grid-stride loop). R1's 4-iter loop
//    serialized load->store batches per iteration (vmcnt drain each iter)
//    and cut TLP 8x; kernel regressed 63->84 us at only 2.4 TB/s.
//  - Keep R0's straight-line body but with 4 independent float4 loads
//    batched before 4 nt stores (2x the MLP of R0's 2/thread).
//  - Keep plain (cache-allocating) LOADS: R1 proved L3 serves ~half the
//    input (FETCH 65.5 MB vs 134 MB) — free HBM traffic reduction.
//  - Keep NONTEMPORAL stores: output is never re-read; don't evict input.

typedef float fvec4 __attribute__((ext_vector_type(4)));

__global__ __launch_bounds__(256) void spherical_scale_kernel(
    const fvec4* __restrict__ x4,
    const float* __restrict__ s_ptr,
    fvec4* __restrict__ out4,
    int n4)   // number of fvec4 elements
{
    const float s = fabsf(s_ptr[0]);
    const int nthreads = gridDim.x * blockDim.x;   // covers n4/4
    const int i = blockIdx.x * blockDim.x + threadIdx.x;

    const int i1 = i + nthreads;
    const int i2 = i + 2 * nthreads;
    const int i3 = i + 3 * nthreads;

    if (i3 < n4) {
        // Fast path: 4 independent loads issued back-to-back (one vmcnt
        // batch), then 4 nt stores. Lane-contiguous per instruction.
        fvec4 a = x4[i];
        fvec4 b = x4[i1];
        fvec4 c = x4[i2];
        fvec4 d = x4[i3];
        a *= s;
        b *= s;
        c *= s;
        d *= s;
        __builtin_nontemporal_store(a, &out4[i]);
        __builtin_nontemporal_store(b, &out4[i1]);
        __builtin_nontemporal_store(c, &out4[i2]);
        __builtin_nontemporal_store(d, &out4[i3]);
    } else {
        // Tail (unused for 8192x4096: 8388608 / 1024 = 8192 exact).
        for (int j = i; j < n4; j += nthreads) {
            fvec4 a = x4[j];
            a *= s;
            __builtin_nontemporal_store(a, &out4[j]);
        }
    }
}

extern "C" void kernel_launch(void* const* d_in, const int* in_sizes, int n_in,
                              void* d_out, int out_size, void* d_ws, size_t ws_size,
                              hipStream_t stream) {
    const float* x = (const float*)d_in[0];
    const float* s = (const float*)d_in[1];
    float* out = (float*)d_out;

    const int n = in_sizes[0];        // 8192*4096 = 33554432 floats
    const int n4 = n / 4;             // 8388608 fvec4s
    const int block = 256;
    const int per_thread = 4;         // float4s per thread
    const int total_threads = (n4 + per_thread - 1) / per_thread;
    const int grid = (total_threads + block - 1) / block;   // 8192

    spherical_scale_kernel<<<grid, block, 0, stream>>>(
        (const fvec4*)x, s, (fvec4*)out, n4);
}

// Round 3
// 229.928 us; speedup vs baseline: 1.0467x; 1.0467x over previous
//
#include <hip/hip_runtime.h>

// Spherical: out = x * |s|  (x: 8192x4096 fp32, s: scalar fp32)
// Pure streaming scale — memory-bound, zero reuse.
//
// R3: A/B on the load cache-policy bit, structure held at R2's.
//   Evidence: R1 (loop, 2048blk, plain loads) = 83.8us and R2 (flat,
//   8192blk, plain loads) = 85-87us are equal despite different
//   structures; R0 (flat, nt loads) = ~60us. Only surviving causal
//   variable = nontemporal on loads. Theory: plain loads ALLOCATE into
//   the 4MiB/XCD L2 while streaming 128MiB -> allocate/evict serializes
//   against the nt-store stream; nt loads bypass allocation.
//   (R1/R2 proved the "L3 serves half the reads" FETCH win is real but
//   worthless - read bytes were never the limiter.)
//
//  - NONTEMPORAL loads (restored) + NONTEMPORAL stores.
//  - Flat exact-cover grid, 4 independent float4/thread, batched
//    loads then batched stores (identical to R2 otherwise).

typedef float fvec4 __attribute__((ext_vector_type(4)));

__global__ __launch_bounds__(256) void spherical_scale_kernel(
    const fvec4* __restrict__ x4,
    const float* __restrict__ s_ptr,
    fvec4* __restrict__ out4,
    int n4)   // number of fvec4 elements
{
    const float s = fabsf(s_ptr[0]);
    const int nthreads = gridDim.x * blockDim.x;
    const int i = blockIdx.x * blockDim.x + threadIdx.x;

    const int i1 = i + nthreads;
    const int i2 = i + 2 * nthreads;
    const int i3 = i + 3 * nthreads;

    if (i3 < n4) {
        fvec4 a = __builtin_nontemporal_load(&x4[i]);
        fvec4 b = __builtin_nontemporal_load(&x4[i1]);
        fvec4 c = __builtin_nontemporal_load(&x4[i2]);
        fvec4 d = __builtin_nontemporal_load(&x4[i3]);
        a *= s;
        b *= s;
        c *= s;
        d *= s;
        __builtin_nontemporal_store(a, &out4[i]);
        __builtin_nontemporal_store(b, &out4[i1]);
        __builtin_nontemporal_store(c, &out4[i2]);
        __builtin_nontemporal_store(d, &out4[i3]);
    } else {
        // Tail (unused for 8192x4096: exact cover).
        for (int j = i; j < n4; j += nthreads) {
            fvec4 a = __builtin_nontemporal_load(&x4[j]);
            a *= s;
            __builtin_nontemporal_store(a, &out4[j]);
        }
    }
}

extern "C" void kernel_launch(void* const* d_in, const int* in_sizes, int n_in,
                              void* d_out, int out_size, void* d_ws, size_t ws_size,
                              hipStream_t stream) {
    const float* x = (const float*)d_in[0];
    const float* s = (const float*)d_in[1];
    float* out = (float*)d_out;

    const int n = in_sizes[0];        // 8192*4096 = 33554432 floats
    const int n4 = n / 4;             // 8388608 fvec4s
    const int block = 256;
    const int per_thread = 4;         // float4s per thread
    const int total_threads = (n4 + per_thread - 1) / per_thread;
    const int grid = (total_threads + block - 1) / block;   // 8192

    spherical_scale_kernel<<<grid, block, 0, stream>>>(
        (const fvec4*)x, s, (fvec4*)out, n4);
}

// Round 4
// 218.158 us; speedup vs baseline: 1.1032x; 1.0540x over previous
//
#include <hip/hip_runtime.h>

// Spherical: out = x * |s|  (x: 8192x4096 fp32, s: scalar fp32)
// Pure streaming scale — memory-bound, zero reuse.
//
// R4: depth-curve test. nt-family results so far (hints held fixed at
// nt-load + nt-store, flat exact-cover grid):
//   depth=4 (8192 blk)  ~74 us   (R3)
//   depth=2 (16384 blk) ~60-63us (R0)
//   depth=1 (32768 blk)  ?       (this round)
// Theory: TLP > ILP for this kernel — wave-switching is free at 12 VGPRs,
// and shallow threads let the CU scheduler interleave load/store streams
// more finely than a per-thread batched load->store burst does.
// R3 established nt-on-loads is causal (+12 us vs plain, despite plain
// halving HBM FETCH via L3 hits — allocation policy, not bytes, matters).

typedef float fvec4 __attribute__((ext_vector_type(4)));

__global__ __launch_bounds__(256) void spherical_scale_kernel(
    const fvec4* __restrict__ x4,
    const float* __restrict__ s_ptr,
    fvec4* __restrict__ out4,
    int n4)   // number of fvec4 elements
{
    const float s = fabsf(s_ptr[0]);
    const int i = blockIdx.x * blockDim.x + threadIdx.x;

    if (i < n4) {
        fvec4 a = __builtin_nontemporal_load(&x4[i]);
        a *= s;
        __builtin_nontemporal_store(a, &out4[i]);
    }
}

extern "C" void kernel_launch(void* const* d_in, const int* in_sizes, int n_in,
                              void* d_out, int out_size, void* d_ws, size_t ws_size,
                              hipStream_t stream) {
    const float* x = (const float*)d_in[0];
    const float* s = (const float*)d_in[1];
    float* out = (float*)d_out;

    const int n = in_sizes[0];        // 8192*4096 = 33554432 floats
    const int n4 = n / 4;             // 8388608 fvec4s
    const int block = 256;
    const int grid = (n4 + block - 1) / block;   // 32768 blocks, 1 fvec4/thread

    spherical_scale_kernel<<<grid, block, 0, stream>>>(
        (const fvec4*)x, s, (fvec4*)out, n4);
}